// Round 9
// baseline (195.599 us; speedup 1.0000x reference)
//
#include <hip/hip_runtime.h>
#include <hip/hip_bf16.h>
#include <stdint.h>

#define BATCH 64
#define CIN   64
#define LEN   4096
#define COUT  128
#define KW    7
#define LPOOL 2048
#define NT    4     // R9: 4 tiles/block -> grid 1024 = 4 blocks/CU offered (3 resident + 1 replacement)
#define RROWS 72    // sign rows: p = l0-4+r, r in [0,72)
#define RAWP  80    // raw floats per ci row: p = l0-8+col, col in [0,80)
#define SPITCH 64   // ushorts per stg row = 128B (XOR-swizzled by (r&7)<<4 bytes)

typedef __bf16 v8bf __attribute__((ext_vector_type(8)));
typedef unsigned short v8us __attribute__((ext_vector_type(8)));
typedef float  v4f  __attribute__((ext_vector_type(4)));

typedef const __attribute__((address_space(1))) void* gp1_t;
typedef __attribute__((address_space(3))) void* lp3_t;

// Convert conv_w [COUT][CIN][KW] fp32 -> Wt [KW][COUT][CIN] bf16 (RNE).
__global__ __launch_bounds__(256)
void wconv_kernel(const float* __restrict__ W, ushort* __restrict__ Wt) {
    int i = blockIdx.x * 256 + threadIdx.x;
    if (i >= COUT * CIN * KW) return;
    int co  = i / (CIN * KW);
    int rem = i - co * (CIN * KW);
    int ci  = rem / KW;
    int k   = rem - ci * KW;
    uint u = __float_as_uint(W[i]);
    uint r = (u + 0x7FFFu + ((u >> 16) & 1u)) >> 16;   // RNE to bf16
    Wt[(k * COUT + co) * CIN + ci] = (ushort)r;
}

// lgkm-only barrier: LDS visibility without draining vmcnt.
static __device__ __forceinline__ void sync_lds() {
    asm volatile("s_waitcnt lgkmcnt(0)" ::: "memory");
    __builtin_amdgcn_s_barrier();
}
static __device__ __forceinline__ void wait_vm0() {
    asm volatile("s_waitcnt vmcnt(0)" ::: "memory");
}

// Fused: BN -> sign -> conv (bf16 MFMA) -> alpha -> PReLU -> maxpool2.
// R9 — restore wave count under the R8 structure. R8 (W register-resident,
// VMEM-free k-loop, NT=8) was the session's first real win: 87 -> 70us,
// MfmaUtil 13 -> 16, occupancy 18% (2 blocks/CU, 2 waves/SIMD — the
// deliberate cost). All pipes still <=30% => latency-bound with the
// thinnest possible wave cover. One knob: NT 8->4, grid 1024 = 4
// blocks/CU offered. Residency: LDS 38912B -> 4 fit; unified regs ~160
// (VGPR 128 + acc AGPRs) -> 12 waves/CU = 3 blocks resident + 1 queued
// replacement (covers retire-skew that R8's exact-fit grid couldn't).
// W reloads per block are L2-hot (~3us aggregate, absorbed). Inner code
// byte-identical to R8 (verified): pure ds_read->MFMA k-loop with
// per-tap sched_barrier(0), dbuf stg, wave-private DMA, lgkm-only
// barriers. Numerics identical.
__global__ __launch_bounds__(256, 2)
void conv_kernel(const float* __restrict__ I,
                 const float* __restrict__ bn_g, const float* __restrict__ bn_b,
                 const float* __restrict__ bn_m, const float* __restrict__ bn_v,
                 const ushort* __restrict__ Wt,
                 const float* __restrict__ alpha, const float* __restrict__ prelu,
                 float* __restrict__ out) {
    __shared__ __attribute__((aligned(16))) float  raw[CIN * RAWP];        // 20480 B, wave-private quarters
    __shared__ __attribute__((aligned(16))) ushort stg[2][RROWS * SPITCH]; // 2 x 9216 B

    int tid = threadIdx.x;
    int lane = tid & 63, wave = tid >> 6;
    int b = blockIdx.y, bx = blockIdx.x;
    int l0base = bx * (64 * NT);

    const float* Ib = I + (size_t)b * CIN * LEN;

    // Wave-private DMA plan (R3, verified): wave w owns ci [16w,16w+16) =
    // 320 float4 chunks = 5 slots x 64 lanes. Chunk m = i*64+lane =
    // cil*20 + c lands at rawb float m*4 (HW: uniform base rawb+i*256 +
    // lane*16B); global p = l0-8+4c+(0..3).
    float* rawb = raw + wave * 1280;
    const char* gb[5]; int cb[5];
    #pragma unroll
    for (int i = 0; i < 5; ++i) {
        int m = i * 64 + lane;
        int cil = m / 20;
        int c   = m - 20 * cil;
        cb[i] = 16 * c - 32;                                  // byte offset before +4*l0
        gb[i] = (const char*)(Ib + (size_t)(16 * wave + cil) * LEN) + cb[i];
    }

    auto dma_tile = [&](int l0t) {
        int l4 = 4 * l0t;
        #pragma unroll
        for (int i = 0; i < 5; ++i) {
            int off = cb[i] + l4;
            if (off >= 0 && off + 16 <= LEN * 4)
                __builtin_amdgcn_global_load_lds((gp1_t)(gb[i] + l4),
                                                 (lp3_t)(rawb + i * 256), 16, 0, 0);
        }
    };

    dma_tile(l0base);            // DMA(0); raw single-buffered, one DMA in flight

    // ---- per-lane BN consts (t-invariant): lanes<36 of each wave handle
    // the wave's two ci-octets (g8 = 2*wave + (lane&1)) at row-quad lane>>1.
    int oc  = lane & 1;
    int brq = lane >> 1;              // 0..17 for lanes 0..35
    int g8  = 2 * wave + oc;
    float sc[8], mn[8], bt[8];
    if (lane < 36) {
        #pragma unroll
        for (int c = 0; c < 8; ++c) {
            int ci = 8 * g8 + c;
            // bit-exact vs np fp32: gamma / sqrt(var + eps)
            sc[c] = __fdiv_rn(bn_g[ci], __fsqrt_rn(__fadd_rn(bn_v[ci], 1e-5f)));
            mn[c] = bn_m[ci];
            bt[c] = bn_b[ci];
        }
    }

    int quad = lane >> 4, lr = lane & 15;
    int cout0 = wave * 32;
    const ushort* wbase = Wt + ((size_t)cout0 + lr) * CIN + quad * 8;
    float pw  = prelu[0];
    float al0 = alpha[cout0 + lr];
    float al1 = alpha[cout0 + 16 + lr];
    float* obase = out + ((size_t)b * COUT) * LPOOL + bx * (32 * NT);

    // ---- W fully register-resident: 28 x v8bf = 112 VGPRs, loaded once.
    // wreg[k][h][n2]: h = ci half (+32 ushorts), n2 = co half (+16*CIN).
    v8bf wreg[KW][2][2];
    #pragma unroll
    for (int k = 0; k < KW; ++k) {
        const ushort* wk = wbase + (size_t)k * COUT * CIN;
        wreg[k][0][0] = *(const v8bf*)(wk);
        wreg[k][0][1] = *(const v8bf*)(wk + 16 * CIN);
        wreg[k][1][0] = *(const v8bf*)(wk + 32);
        wreg[k][1][1] = *(const v8bf*)(wk + 32 + 16 * CIN);
    }

    // binarize(tile): wave-private raw -> stg[buf]. Caller guarantees this
    // wave's DMA for the tile has drained (wait_vm0) before calling.
    auto binarize = [&](int l0t, int buf) {
        if (lane < 36) {
            const float4* r4 = (const float4*)rawb;
            float4 fr[8];
            #pragma unroll
            for (int c = 0; c < 8; ++c)
                fr[c] = r4[(8 * oc + c) * 20 + brq + 1];
            ushort* sb = &stg[buf][0];
            #pragma unroll
            for (int j = 0; j < 4; ++j) {
                int r = 4 * brq + j;
                int p = l0t - 4 + r;
                bool pok = (p >= 0) && (p < LEN);
                v8us u;
                #pragma unroll
                for (int c = 0; c < 8; ++c) {
                    float v = ((const float*)&fr[c])[j];
                    // (v - mean) * scale + beta, exact np rounding (sign boundary)
                    float x = __fadd_rn(__fmul_rn(__fsub_rn(v, mn[c]), sc[c]), bt[c]);
                    ushort s = x > 0.f ? (ushort)0x3F80 : (x < 0.f ? (ushort)0xBF80 : (ushort)0);
                    u[c] = pok ? s : (ushort)0;
                }
                *(v8us*)(&sb[r * SPITCH + ((g8 ^ (r & 7)) << 3)]) = u;
            }
        }
    };

    wait_vm0();                 // own DMA(0) + W/const loads landed
    binarize(l0base, 0);        // consume raw(0); raw free again
    dma_tile(l0base + 64);      // DMA(1)
    sync_lds();                 // stg[0] visible to all waves

    for (int t = 0; t < NT; ++t) {
        int l0 = l0base + t * 64;
        const ushort* sb_cur = &stg[t & 1][0];

        // ---- MFMA(t): pure ds_read -> MFMA, zero VMEM in the loop ----
        v4f acc[4][2];
        #pragma unroll
        for (int mt = 0; mt < 4; ++mt) { acc[mt][0] = (v4f)0.f; acc[mt][1] = (v4f)0.f; }

        #pragma unroll
        for (int k = 0; k < KW; ++k) {
            // A row for output l=mt*16+lr at tap k: r = l + k + 1; (r&7) mt-invariant
            int rk = lr + 1 + k;
            int s8 = rk & 7;
            const ushort* a0p = &sb_cur[rk * SPITCH + ((quad ^ s8) << 3)];        // ci 0..31
            const ushort* a1p = &sb_cur[rk * SPITCH + (((quad ^ 4) ^ s8) << 3)];  // ci 32..63
            #pragma unroll
            for (int mt = 0; mt < 4; ++mt) {
                v8bf a0 = *(const v8bf*)(a0p + mt * 16 * SPITCH);
                v8bf a1 = *(const v8bf*)(a1p + mt * 16 * SPITCH);
                acc[mt][0] = __builtin_amdgcn_mfma_f32_16x16x32_bf16(a0, wreg[k][0][0], acc[mt][0], 0, 0, 0);
                acc[mt][1] = __builtin_amdgcn_mfma_f32_16x16x32_bf16(a0, wreg[k][0][1], acc[mt][1], 0, 0, 0);
                acc[mt][0] = __builtin_amdgcn_mfma_f32_16x16x32_bf16(a1, wreg[k][1][0], acc[mt][0], 0, 0, 0);
                acc[mt][1] = __builtin_amdgcn_mfma_f32_16x16x32_bf16(a1, wreg[k][1][1], acc[mt][1], 0, 0, 0);
            }
            // scheduling fence: cap in-flight ds_reads at one tap's worth (8)
            // to prevent the 56-read batching spill seen with full unroll.
            __builtin_amdgcn_sched_barrier(0);
        }

        // ---- pool-compute: acc -> pooled pv ----
        float pv[2][4][2];
        #pragma unroll
        for (int n2 = 0; n2 < 2; ++n2) {
            float al = n2 ? al1 : al0;
            #pragma unroll
            for (int mt = 0; mt < 4; ++mt) {
                float v0 = acc[mt][n2][0] * al; v0 = v0 > 0.f ? v0 : pw * v0;
                float v1 = acc[mt][n2][1] * al; v1 = v1 > 0.f ? v1 : pw * v1;
                float v2 = acc[mt][n2][2] * al; v2 = v2 > 0.f ? v2 : pw * v2;
                float v3 = acc[mt][n2][3] * al; v3 = v3 > 0.f ? v3 : pw * v3;
                pv[n2][mt][0] = fmaxf(v0, v1);
                pv[n2][mt][1] = fmaxf(v2, v3);
            }
        }

        // ---- binarize(t+1): own DMA(t+1) is >=1 phase old -> vmcnt(0) ~free;
        //      then DMA(t+2) into the freed raw. ----
        if (t + 1 < NT) {
            wait_vm0();
            binarize(l0 + 64, (t + 1) & 1);
        }
        if (t + 2 < NT) dma_tile(l0 + 128);

        // ---- stores(t): issued last, drain under next k-loop ----
        float* ob = obase + t * 32;
        #pragma unroll
        for (int n2 = 0; n2 < 2; ++n2) {
            int co = cout0 + n2 * 16 + lr;
            float* ocp = ob + (size_t)co * LPOOL + quad * 2;
            #pragma unroll
            for (int mt = 0; mt < 4; ++mt)
                *(float2*)(ocp + mt * 8) = make_float2(pv[n2][mt][0], pv[n2][mt][1]);
        }

        sync_lds();   // lgkm-only: stg[nb] visible; stores/DMA stay in flight
    }
}

extern "C" void kernel_launch(void* const* d_in, const int* in_sizes, int n_in,
                              void* d_out, int out_size, void* d_ws, size_t ws_size,
                              hipStream_t stream) {
    const float* I      = (const float*)d_in[0];
    const float* bn_g   = (const float*)d_in[1];
    const float* bn_b   = (const float*)d_in[2];
    const float* bn_m   = (const float*)d_in[3];
    const float* bn_v   = (const float*)d_in[4];
    const float* conv_w = (const float*)d_in[5];
    const float* alpha  = (const float*)d_in[6];
    const float* prelu  = (const float*)d_in[7];
    float* out = (float*)d_out;

    ushort* Wt = (ushort*)d_ws;   // 7*128*64*2 = 114688 bytes

    wconv_kernel<<<(COUT * CIN * KW + 255) / 256, 256, 0, stream>>>(conv_w, Wt);
    dim3 grid(LEN / (64 * NT), BATCH);   // 16 x 64 = 1024 blocks = 4/CU offered
    conv_kernel<<<grid, 256, 0, stream>>>(I, bn_g, bn_b, bn_m, bn_v, Wt, alpha, prelu, out);
}

// Round 10
// 166.547 us; speedup vs baseline: 1.1744x; 1.1744x over previous
//
#include <hip/hip_runtime.h>
#include <hip/hip_bf16.h>
#include <stdint.h>

#define BATCH 64
#define CIN   64
#define LEN   4096
#define COUT  128
#define KW    7
#define LPOOL 2048
#define NT    4     // 4 tiles/block -> grid 1024 = 4 blocks/CU offered
#define RROWS 72    // sign rows: p = l0-4+r, r in [0,72)
#define RAWP  80    // raw floats per ci row: p = l0-8+col, col in [0,80)
#define SPITCH 64   // ushorts per stg row = 128B (XOR-swizzled by (r&7)<<4 bytes)

typedef __bf16 v8bf __attribute__((ext_vector_type(8)));
typedef unsigned short v8us __attribute__((ext_vector_type(8)));
typedef float  v4f  __attribute__((ext_vector_type(4)));

typedef const __attribute__((address_space(1))) void* gp1_t;
typedef __attribute__((address_space(3))) void* lp3_t;

// Convert conv_w [COUT][CIN][KW] fp32 -> Wt [KW][COUT][CIN] bf16 (RNE).
__global__ __launch_bounds__(256)
void wconv_kernel(const float* __restrict__ W, ushort* __restrict__ Wt) {
    int i = blockIdx.x * 256 + threadIdx.x;
    if (i >= COUT * CIN * KW) return;
    int co  = i / (CIN * KW);
    int rem = i - co * (CIN * KW);
    int ci  = rem / KW;
    int k   = rem - ci * KW;
    uint u = __float_as_uint(W[i]);
    uint r = (u + 0x7FFFu + ((u >> 16) & 1u)) >> 16;   // RNE to bf16
    Wt[(k * COUT + co) * CIN + ci] = (ushort)r;
}

// lgkm-only barrier: LDS visibility without draining vmcnt.
static __device__ __forceinline__ void sync_lds() {
    asm volatile("s_waitcnt lgkmcnt(0)" ::: "memory");
    __builtin_amdgcn_s_barrier();
}
static __device__ __forceinline__ void wait_vm0() {
    asm volatile("s_waitcnt vmcnt(0)" ::: "memory");
}

// Fused: BN -> sign -> conv (bf16 MFMA) -> alpha -> PReLU -> maxpool2.
// R10 — R9 de-confounded. R9 (NT 8->4) regressed 70->98us with FETCH and
// WRITE each +57MB (symmetric) = scratch spill traffic: with trip count
// 4 the compiler fully UNROLLED the t-loop -> 4 live k-loop bodies ->
// register demand past the (256,2) budget -> ~55 dwords/thread spilled.
// The occupancy experiment was never run. Fix: #pragma unroll 1 on the
// t-loop (only change vs R9). Everything else is R8's verified code:
//  - W register-resident (112 VGPR), pure ds_read->MFMA k-loop with
//    per-tap sched_barrier(0), zero VMEM in the loop
//  - wave-private DMA (uniform LDS base), dbuf stg, lgkm-only barriers
//  - grid 1024 = 4 blocks/CU offered (the occupancy lever under test)
// Numerics identical.
__global__ __launch_bounds__(256, 2)
void conv_kernel(const float* __restrict__ I,
                 const float* __restrict__ bn_g, const float* __restrict__ bn_b,
                 const float* __restrict__ bn_m, const float* __restrict__ bn_v,
                 const ushort* __restrict__ Wt,
                 const float* __restrict__ alpha, const float* __restrict__ prelu,
                 float* __restrict__ out) {
    __shared__ __attribute__((aligned(16))) float  raw[CIN * RAWP];        // 20480 B, wave-private quarters
    __shared__ __attribute__((aligned(16))) ushort stg[2][RROWS * SPITCH]; // 2 x 9216 B

    int tid = threadIdx.x;
    int lane = tid & 63, wave = tid >> 6;
    int b = blockIdx.y, bx = blockIdx.x;
    int l0base = bx * (64 * NT);

    const float* Ib = I + (size_t)b * CIN * LEN;

    // Wave-private DMA plan (R3, verified): wave w owns ci [16w,16w+16) =
    // 320 float4 chunks = 5 slots x 64 lanes. Chunk m = i*64+lane =
    // cil*20 + c lands at rawb float m*4 (HW: uniform base rawb+i*256 +
    // lane*16B); global p = l0-8+4c+(0..3).
    float* rawb = raw + wave * 1280;
    const char* gb[5]; int cb[5];
    #pragma unroll
    for (int i = 0; i < 5; ++i) {
        int m = i * 64 + lane;
        int cil = m / 20;
        int c   = m - 20 * cil;
        cb[i] = 16 * c - 32;                                  // byte offset before +4*l0
        gb[i] = (const char*)(Ib + (size_t)(16 * wave + cil) * LEN) + cb[i];
    }

    auto dma_tile = [&](int l0t) {
        int l4 = 4 * l0t;
        #pragma unroll
        for (int i = 0; i < 5; ++i) {
            int off = cb[i] + l4;
            if (off >= 0 && off + 16 <= LEN * 4)
                __builtin_amdgcn_global_load_lds((gp1_t)(gb[i] + l4),
                                                 (lp3_t)(rawb + i * 256), 16, 0, 0);
        }
    };

    dma_tile(l0base);            // DMA(0); raw single-buffered, one DMA in flight

    // ---- per-lane BN consts (t-invariant): lanes<36 of each wave handle
    // the wave's two ci-octets (g8 = 2*wave + (lane&1)) at row-quad lane>>1.
    int oc  = lane & 1;
    int brq = lane >> 1;              // 0..17 for lanes 0..35
    int g8  = 2 * wave + oc;
    float sc[8], mn[8], bt[8];
    if (lane < 36) {
        #pragma unroll
        for (int c = 0; c < 8; ++c) {
            int ci = 8 * g8 + c;
            // bit-exact vs np fp32: gamma / sqrt(var + eps)
            sc[c] = __fdiv_rn(bn_g[ci], __fsqrt_rn(__fadd_rn(bn_v[ci], 1e-5f)));
            mn[c] = bn_m[ci];
            bt[c] = bn_b[ci];
        }
    }

    int quad = lane >> 4, lr = lane & 15;
    int cout0 = wave * 32;
    const ushort* wbase = Wt + ((size_t)cout0 + lr) * CIN + quad * 8;
    float pw  = prelu[0];
    float al0 = alpha[cout0 + lr];
    float al1 = alpha[cout0 + 16 + lr];
    float* obase = out + ((size_t)b * COUT) * LPOOL + bx * (32 * NT);

    // ---- W fully register-resident: 28 x v8bf = 112 VGPRs, loaded once.
    // wreg[k][h][n2]: h = ci half (+32 ushorts), n2 = co half (+16*CIN).
    v8bf wreg[KW][2][2];
    #pragma unroll
    for (int k = 0; k < KW; ++k) {
        const ushort* wk = wbase + (size_t)k * COUT * CIN;
        wreg[k][0][0] = *(const v8bf*)(wk);
        wreg[k][0][1] = *(const v8bf*)(wk + 16 * CIN);
        wreg[k][1][0] = *(const v8bf*)(wk + 32);
        wreg[k][1][1] = *(const v8bf*)(wk + 32 + 16 * CIN);
    }

    // binarize(tile): wave-private raw -> stg[buf]. Caller guarantees this
    // wave's DMA for the tile has drained (wait_vm0) before calling.
    auto binarize = [&](int l0t, int buf) {
        if (lane < 36) {
            const float4* r4 = (const float4*)rawb;
            float4 fr[8];
            #pragma unroll
            for (int c = 0; c < 8; ++c)
                fr[c] = r4[(8 * oc + c) * 20 + brq + 1];
            ushort* sb = &stg[buf][0];
            #pragma unroll
            for (int j = 0; j < 4; ++j) {
                int r = 4 * brq + j;
                int p = l0t - 4 + r;
                bool pok = (p >= 0) && (p < LEN);
                v8us u;
                #pragma unroll
                for (int c = 0; c < 8; ++c) {
                    float v = ((const float*)&fr[c])[j];
                    // (v - mean) * scale + beta, exact np rounding (sign boundary)
                    float x = __fadd_rn(__fmul_rn(__fsub_rn(v, mn[c]), sc[c]), bt[c]);
                    ushort s = x > 0.f ? (ushort)0x3F80 : (x < 0.f ? (ushort)0xBF80 : (ushort)0);
                    u[c] = pok ? s : (ushort)0;
                }
                *(v8us*)(&sb[r * SPITCH + ((g8 ^ (r & 7)) << 3)]) = u;
            }
        }
    };

    wait_vm0();                 // own DMA(0) + W/const loads landed
    binarize(l0base, 0);        // consume raw(0); raw free again
    dma_tile(l0base + 64);      // DMA(1)
    sync_lds();                 // stg[0] visible to all waves

    #pragma unroll 1            // R10: MUST stay rolled — full unroll at NT=4
    for (int t = 0; t < NT; ++t) {   // spilled ~55 dwords/thread (R9: +57MB FETCH & WRITE)
        int l0 = l0base + t * 64;
        const ushort* sb_cur = &stg[t & 1][0];

        // ---- MFMA(t): pure ds_read -> MFMA, zero VMEM in the loop ----
        v4f acc[4][2];
        #pragma unroll
        for (int mt = 0; mt < 4; ++mt) { acc[mt][0] = (v4f)0.f; acc[mt][1] = (v4f)0.f; }

        #pragma unroll
        for (int k = 0; k < KW; ++k) {
            // A row for output l=mt*16+lr at tap k: r = l + k + 1; (r&7) mt-invariant
            int rk = lr + 1 + k;
            int s8 = rk & 7;
            const ushort* a0p = &sb_cur[rk * SPITCH + ((quad ^ s8) << 3)];        // ci 0..31
            const ushort* a1p = &sb_cur[rk * SPITCH + (((quad ^ 4) ^ s8) << 3)];  // ci 32..63
            #pragma unroll
            for (int mt = 0; mt < 4; ++mt) {
                v8bf a0 = *(const v8bf*)(a0p + mt * 16 * SPITCH);
                v8bf a1 = *(const v8bf*)(a1p + mt * 16 * SPITCH);
                acc[mt][0] = __builtin_amdgcn_mfma_f32_16x16x32_bf16(a0, wreg[k][0][0], acc[mt][0], 0, 0, 0);
                acc[mt][1] = __builtin_amdgcn_mfma_f32_16x16x32_bf16(a0, wreg[k][0][1], acc[mt][1], 0, 0, 0);
                acc[mt][0] = __builtin_amdgcn_mfma_f32_16x16x32_bf16(a1, wreg[k][1][0], acc[mt][0], 0, 0, 0);
                acc[mt][1] = __builtin_amdgcn_mfma_f32_16x16x32_bf16(a1, wreg[k][1][1], acc[mt][1], 0, 0, 0);
            }
            // scheduling fence: cap in-flight ds_reads at one tap's worth (8)
            // to prevent the 56-read batching spill seen with full unroll.
            __builtin_amdgcn_sched_barrier(0);
        }

        // ---- pool-compute: acc -> pooled pv ----
        float pv[2][4][2];
        #pragma unroll
        for (int n2 = 0; n2 < 2; ++n2) {
            float al = n2 ? al1 : al0;
            #pragma unroll
            for (int mt = 0; mt < 4; ++mt) {
                float v0 = acc[mt][n2][0] * al; v0 = v0 > 0.f ? v0 : pw * v0;
                float v1 = acc[mt][n2][1] * al; v1 = v1 > 0.f ? v1 : pw * v1;
                float v2 = acc[mt][n2][2] * al; v2 = v2 > 0.f ? v2 : pw * v2;
                float v3 = acc[mt][n2][3] * al; v3 = v3 > 0.f ? v3 : pw * v3;
                pv[n2][mt][0] = fmaxf(v0, v1);
                pv[n2][mt][1] = fmaxf(v2, v3);
            }
        }

        // ---- binarize(t+1): own DMA(t+1) is >=1 phase old -> vmcnt(0) ~free;
        //      then DMA(t+2) into the freed raw. ----
        if (t + 1 < NT) {
            wait_vm0();
            binarize(l0 + 64, (t + 1) & 1);
        }
        if (t + 2 < NT) dma_tile(l0 + 128);

        // ---- stores(t): issued last, drain under next k-loop ----
        float* ob = obase + t * 32;
        #pragma unroll
        for (int n2 = 0; n2 < 2; ++n2) {
            int co = cout0 + n2 * 16 + lr;
            float* ocp = ob + (size_t)co * LPOOL + quad * 2;
            #pragma unroll
            for (int mt = 0; mt < 4; ++mt)
                *(float2*)(ocp + mt * 8) = make_float2(pv[n2][mt][0], pv[n2][mt][1]);
        }

        sync_lds();   // lgkm-only: stg[nb] visible; stores/DMA stay in flight
    }
}

extern "C" void kernel_launch(void* const* d_in, const int* in_sizes, int n_in,
                              void* d_out, int out_size, void* d_ws, size_t ws_size,
                              hipStream_t stream) {
    const float* I      = (const float*)d_in[0];
    const float* bn_g   = (const float*)d_in[1];
    const float* bn_b   = (const float*)d_in[2];
    const float* bn_m   = (const float*)d_in[3];
    const float* bn_v   = (const float*)d_in[4];
    const float* conv_w = (const float*)d_in[5];
    const float* alpha  = (const float*)d_in[6];
    const float* prelu  = (const float*)d_in[7];
    float* out = (float*)d_out;

    ushort* Wt = (ushort*)d_ws;   // 7*128*64*2 = 114688 bytes

    wconv_kernel<<<(COUT * CIN * KW + 255) / 256, 256, 0, stream>>>(conv_w, Wt);
    dim3 grid(LEN / (64 * NT), BATCH);   // 16 x 64 = 1024 blocks = 4/CU offered
    conv_kernel<<<grid, 256, 0, stream>>>(I, bn_g, bn_b, bn_m, bn_v, Wt, alpha, prelu, out);
}